// Round 15
// baseline (200.268 us; speedup 1.0000x reference)
//
#include <hip/hip_runtime.h>
#include <math.h>

// Pin FP contraction OFF (r8-r14 proven): every a*b+c stays rounded mul +
// rounded add. Explicit fmaf used only where exact (+-1).
#pragma clang fp contract(off)

#define EPSF 1e-10f
#define INV128 0.0078125f
#define C128 0.08838834764831845f   // np.float32(1/sqrt(128))

struct CbArg { float cb[128]; };

// ---------------- cross-lane primitives (r5/r9 HW-verified, pure DPP) -------
template<int CTRL>
__device__ __forceinline__ float fdpp(float v) {
    return __builtin_bit_cast(float,
        __builtin_amdgcn_update_dpp(0, __builtin_bit_cast(int, v), CTRL, 0xF, 0xF, true));
}
// xor4 as pure DPP: banks 0,2 take row_ror:4; banks 1,3 take row_ror:12.
__device__ __forceinline__ float dpp_xor4(float v) {
    const int x = __builtin_bit_cast(int, v);
    int t = __builtin_amdgcn_update_dpp(x, x, 0x124, 0xF, 0x5, false);
    t = __builtin_amdgcn_update_dpp(t, x, 0x12C, 0xF, 0xA, false);
    return __builtin_bit_cast(float, t);
}
// MODE 1: DPP (verified at runtime) | MODE 0: __shfl_xor fallback
template<int MODE, int D>
__device__ __forceinline__ float xl(float v) {
    if constexpr (MODE == 0)   return __shfl_xor(v, D, 64);
    else if constexpr (D == 1) return fdpp<0xB1>(v);   // quad_perm xor1
    else if constexpr (D == 2) return fdpp<0x4E>(v);   // quad_perm xor2
    else                       return dpp_xor4(v);     // xor4
}

__device__ __forceinline__ bool dpp_ok() {
    const int lane = threadIdx.x & 63;
    const float tv = __int_as_float(0x3f800000 + lane * 1024);
    bool ok = true;
    ok = ok && (__float_as_uint(xl<1,1>(tv)) == __float_as_uint(__shfl_xor(tv, 1, 64)));
    ok = ok && (__float_as_uint(xl<1,2>(tv)) == __float_as_uint(__shfl_xor(tv, 2, 64)));
    ok = ok && (__float_as_uint(xl<1,4>(tv)) == __float_as_uint(__shfl_xor(tv, 4, 64)));
    return __all((int)ok) != 0;
}

// ---------------------------------------------------------------------------
// Main kernel, E=16 layout (r12-proven), TWO groups interleaved per wave.
// Per-group arithmetic is token-identical to r12 (bitwise-same output).
// ---------------------------------------------------------------------------
__device__ __forceinline__ float lm_recon(const float4* __restrict__ tbl4, float v) {
    float cf = fminf(fmaxf(fmaf(v, 128.0f, 512.0f), 0.0f), 1023.0f);
    const float4 e = tbl4[(int)cf];
    return (e.x < v) ? e.z : e.y;   // searchsorted side='left'
}

__device__ __forceinline__ void fwht_in16(float* u) {
#pragma unroll
    for (int d = 1; d <= 8; d <<= 1)
#pragma unroll
        for (int j = 0; j < 16; ++j)
            if ((j & d) == 0) {
                const float a = u[j], b = u[j + d];
                u[j] = a + b; u[j + d] = a - b;
            }
}

// dual-group FWHT: phases interleaved for ILP; per-group order == r12
template<int MODE>
__device__ __forceinline__ void fwht128g2(float* ua, float* ub,
                                          float s1, float s2, float s4) {
    fwht_in16(ua);
    fwht_in16(ub);
#pragma unroll
    for (int j = 0; j < 16; ++j) { const float p = xl<MODE,1>(ua[j]); ua[j] = fmaf(s1, ua[j], p); }
#pragma unroll
    for (int j = 0; j < 16; ++j) { const float p = xl<MODE,1>(ub[j]); ub[j] = fmaf(s1, ub[j], p); }
#pragma unroll
    for (int j = 0; j < 16; ++j) { const float p = xl<MODE,2>(ua[j]); ua[j] = fmaf(s2, ua[j], p); }
#pragma unroll
    for (int j = 0; j < 16; ++j) { const float p = xl<MODE,2>(ub[j]); ub[j] = fmaf(s2, ub[j], p); }
#pragma unroll
    for (int j = 0; j < 16; ++j) { const float p = xl<MODE,4>(ua[j]); ua[j] = fmaf(s4, ua[j], p); }
#pragma unroll
    for (int j = 0; j < 16; ++j) { const float p = xl<MODE,4>(ub[j]); ub[j] = fmaf(s4, ub[j], p); }
}

// sum of q[0..15]: same binary tree as r12 (bitwise-identical), then xor 1,2,4
template<int MODE>
__device__ __forceinline__ float rtree(const float* q) {
    float t8[8];
#pragma unroll
    for (int k = 0; k < 8; ++k) t8[k] = q[2 * k] + q[2 * k + 1];
    float t4[4];
#pragma unroll
    for (int k = 0; k < 4; ++k) t4[k] = t8[2 * k] + t8[2 * k + 1];
    const float t2a = t4[0] + t4[1];
    const float t2b = t4[2] + t4[3];
    float s = t2a + t2b;
    s += xl<MODE, 1>(s);
    s += xl<MODE, 2>(s);
    s += xl<MODE, 4>(s);
    return s;
}

template<int MODE>
__device__ __forceinline__ void run_pairs(
        const float* __restrict__ x, float* __restrict__ out,
        const float* __restrict__ rot, const float* __restrict__ qjl,
        const float4* __restrict__ tbl4, int nrows) {
    const int t    = threadIdx.x;
    const int lane = t & 63;
    const int wid  = t >> 6;
    const int sub  = lane & 7;   // 8 lanes per row
    const int grp  = lane >> 3;  // 8 rows per wave-group

    const float s1 = (sub & 1) ? -1.0f : 1.0f;
    const float s2 = (sub & 2) ? -1.0f : 1.0f;
    const float s4 = (sub & 4) ? -1.0f : 1.0f;

    const int npairs  = nrows >> 4;    // pair P = groups {2P, 2P+1} = 16 rows
    const int wstride = gridDim.x * 4;

    for (int P = blockIdx.x * 4 + wid; P < npairs; P += wstride) {
        const int rowA = P * 16 + grp;
        const int rowB = P * 16 + 8 + grp;

        float ua[16], ub[16], qa[16], qb[16], c0[16];
        {
            const float* xa = x + (size_t)rowA * 128 + sub * 16;
            const float* xb = x + (size_t)rowB * 128 + sub * 16;
#pragma unroll
            for (int k = 0; k < 4; ++k) {
                const float4 v4 = ((const float4*)xa)[k];
                ua[4*k] = v4.x; ua[4*k+1] = v4.y; ua[4*k+2] = v4.z; ua[4*k+3] = v4.w;
            }
#pragma unroll
            for (int k = 0; k < 4; ++k) {
                const float4 v4 = ((const float4*)xb)[k];
                ub[4*k] = v4.x; ub[4*k+1] = v4.y; ub[4*k+2] = v4.z; ub[4*k+3] = v4.w;
            }
        }

        // ---- norms, unit vectors ----
#pragma unroll
        for (int j = 0; j < 16; ++j) { qa[j] = ua[j] * ua[j]; qb[j] = ub[j] * ub[j]; }
        const float nua = sqrtf(rtree<MODE>(qa));
        const float nub = sqrtf(rtree<MODE>(qb));
        const float iua = 1.0f / (nua + EPSF);
        const float iub = 1.0f / (nub + EPSF);

#pragma unroll
        for (int k = 0; k < 4; ++k) {   // rs0 (global/L1, shared by A,B)
            const float4 v4 = ((const float4*)(rot + sub * 16))[k];
            c0[4*k] = v4.x; c0[4*k+1] = v4.y; c0[4*k+2] = v4.z; c0[4*k+3] = v4.w;
        }
#pragma unroll
        for (int j = 0; j < 16; ++j) {
            ua[j] = ua[j] * iua; ua[j] = ua[j] * c0[j];
            ub[j] = ub[j] * iub; ub[j] = ub[j] * c0[j];
        }

        // ---- rotation_fwd (normalized; feeds quantizer) ----
        fwht128g2<MODE>(ua, ub, s1, s2, s4);
#pragma unroll
        for (int j = 0; j < 16; ++j) { ua[j] *= C128; ub[j] *= C128; }
#pragma unroll
        for (int k = 0; k < 4; ++k) {   // rs1
            const float4 v4 = ((const float4*)(rot + 128 + sub * 16))[k];
            c0[4*k] = v4.x; c0[4*k+1] = v4.y; c0[4*k+2] = v4.z; c0[4*k+3] = v4.w;
        }
#pragma unroll
        for (int j = 0; j < 16; ++j) { ua[j] *= c0[j]; ub[j] *= c0[j]; }
        fwht128g2<MODE>(ua, ub, s1, s2, s4);
#pragma unroll
        for (int j = 0; j < 16; ++j) { ua[j] *= C128; ub[j] *= C128; }

        // ---- pass 1: numerical rms + LM quantize ----
#pragma unroll
        for (int j = 0; j < 16; ++j) { qa[j] = ua[j] * ua[j]; qb[j] = ub[j] * ub[j]; }
        const float rmsa = sqrtf(rtree<MODE>(qa)) * C128;
        const float rmsb = sqrtf(rtree<MODE>(qb)) * C128;
        const float sia  = 1.0f / (rmsa + EPSF);
        const float sib  = 1.0f / (rmsb + EPSF);
#pragma unroll
        for (int j = 0; j < 16; ++j) qa[j] = lm_recon(tbl4, ua[j] * sia);   // r_A
#pragma unroll
        for (int j = 0; j < 16; ++j) qb[j] = lm_recon(tbl4, ub[j] * sib);   // r_B

        // ---- refined gamma ----
        float w[16];
#pragma unroll
        for (int j = 0; j < 16; ++j) w[j] = ua[j] * qa[j];
        const float numa = rtree<MODE>(w);
#pragma unroll
        for (int j = 0; j < 16; ++j) w[j] = ub[j] * qb[j];
        const float numb = rtree<MODE>(w);
#pragma unroll
        for (int j = 0; j < 16; ++j) w[j] = qa[j] * qa[j];
        const float dena = rtree<MODE>(w);
#pragma unroll
        for (int j = 0; j < 16; ++j) w[j] = qb[j] * qb[j];
        const float denb = rtree<MODE>(w);
        const float ga  = numa / (dena + EPSF);
        const float gb  = numb / (denb + EPSF);
        const float gia = 1.0f / (ga + EPSF);
        const float gib = 1.0f / (gb + EPSF);

        // ---- MSE-stage quantize; residuals in pa/pb (qa/qb become rc) ----
        float pa[16], pb[16];
#pragma unroll
        for (int j = 0; j < 16; ++j) {
            const float tq = lm_recon(tbl4, ua[j] * gia);
            qa[j] = tq * ga;            // rc_A
            pa[j] = ua[j] - qa[j];
        }
#pragma unroll
        for (int j = 0; j < 16; ++j) {
            const float tq = lm_recon(tbl4, ub[j] * gib);
            qb[j] = tq * gb;            // rc_B
            pb[j] = ub[j] - qb[j];
        }
#pragma unroll
        for (int j = 0; j < 16; ++j) w[j] = pa[j] * pa[j];
        const float resna = sqrtf(rtree<MODE>(w));
#pragma unroll
        for (int j = 0; j < 16; ++j) w[j] = pb[j] * pb[j];
        const float resnb = sqrtf(rtree<MODE>(w));

        // ==== post-quantization (ulp-safe folds) ====
#pragma unroll
        for (int k = 0; k < 4; ++k) {   // qjl
            const float4 v4 = ((const float4*)(qjl + sub * 16))[k];
            c0[4*k] = v4.x; c0[4*k+1] = v4.y; c0[4*k+2] = v4.z; c0[4*k+3] = v4.w;
        }
#pragma unroll
        for (int j = 0; j < 16; ++j) { pa[j] = pa[j] * c0[j]; pb[j] = pb[j] * c0[j]; }
        fwht128g2<MODE>(pa, pb, s1, s2, s4);
#pragma unroll
        for (int j = 0; j < 16; ++j) {
            pa[j] = (pa[j] >= 0.0f) ? 1.0f : -1.0f;
            pb[j] = (pb[j] >= 0.0f) ? 1.0f : -1.0f;
        }
        fwht128g2<MODE>(pa, pb, s1, s2, s4);   // exact integers
        const float rsa = resna * INV128;
        const float rsb = resnb * INV128;
#pragma unroll
        for (int j = 0; j < 16; ++j) {
            const float ta2 = pa[j] * c0[j];
            const float tb2 = pb[j] * c0[j];
            pa[j] = fmaf(ta2, rsa, qa[j]);
            pb[j] = fmaf(tb2, rsb, qb[j]);
        }

        // ---- inverse rotation (folded scales) ----
        fwht128g2<MODE>(pa, pb, s1, s2, s4);
#pragma unroll
        for (int k = 0; k < 4; ++k) {   // rs1
            const float4 v4 = ((const float4*)(rot + 128 + sub * 16))[k];
            c0[4*k] = v4.x; c0[4*k+1] = v4.y; c0[4*k+2] = v4.z; c0[4*k+3] = v4.w;
        }
#pragma unroll
        for (int j = 0; j < 16; ++j) { pa[j] *= c0[j]; pb[j] *= c0[j]; }
        fwht128g2<MODE>(pa, pb, s1, s2, s4);
#pragma unroll
        for (int k = 0; k < 4; ++k) {   // rs0
            const float4 v4 = ((const float4*)(rot + sub * 16))[k];
            c0[4*k] = v4.x; c0[4*k+1] = v4.y; c0[4*k+2] = v4.z; c0[4*k+3] = v4.w;
        }
        const float fna = nua * INV128;
        const float fnb = nub * INV128;
#pragma unroll
        for (int j = 0; j < 16; ++j) {
            pa[j] = (pa[j] * c0[j]) * fna;
            pb[j] = (pb[j] * c0[j]) * fnb;
        }

        {
            float* oa = out + (size_t)rowA * 128 + sub * 16;
            float* ob = out + (size_t)rowB * 128 + sub * 16;
#pragma unroll
            for (int k = 0; k < 4; ++k) {
                float4 v4;
                v4.x = pa[4*k]; v4.y = pa[4*k+1]; v4.z = pa[4*k+2]; v4.w = pa[4*k+3];
                ((float4*)oa)[k] = v4;
            }
#pragma unroll
            for (int k = 0; k < 4; ++k) {
                float4 v4;
                v4.x = pb[4*k]; v4.y = pb[4*k+1]; v4.z = pb[4*k+2]; v4.w = pb[4*k+3];
                ((float4*)ob)[k] = v4;
            }
        }
    }
}

__global__ __launch_bounds__(256) void turboquant_kernel(
        const float* __restrict__ x,
        const float* __restrict__ rot,
        const float* __restrict__ qjl,
        float* __restrict__ out,
        const int nrows,
        const CbArg args) {
    __shared__ float scb[128];
    __shared__ float sbnd[128];
    __shared__ float4 tbl4[1024];

    const int t = threadIdx.x;
    if (t < 128) scb[t] = args.cb[t];
    __syncthreads();
    if (t < 128) {
        const float INF = __int_as_float(0x7f800000);
        sbnd[t] = (t < 127) ? 0.5f * (scb[t] + scb[t + 1]) : INF;
    }
    __syncthreads();
    // direct cell table (r9/r11/r12-proven): at most one boundary per
    // 1/128-wide cell (min gap ~0.034); g = #bounds < cell_left.
    for (int c = t; c < 1024; c += 256) {
        const float cl = -4.0f + (float)c * 0.0078125f;
        int g = 0;
#pragma unroll
        for (int d = 64; d >= 1; d >>= 1) g += (sbnd[g + d - 1] < cl) ? d : 0;
        tbl4[c] = make_float4(sbnd[g], scb[g], scb[(g < 127) ? g + 1 : 127], 0.0f);
    }
    __syncthreads();

    if (dpp_ok())
        run_pairs<1>(x, out, rot, qjl, tbl4, nrows);
    else
        run_pairs<0>(x, out, rot, qjl, tbl4, nrows);
}

// ---------------------------------------------------------------------------
// Host-side Lloyd-Max (r12-proven): token-identical f64 formulas; runs during
// capture only; kernarg struct snapshotted into the graph node.
// ---------------------------------------------------------------------------
static void lloyd_host(CbArg* out_args) {
    double lv[128], bp[127], bc[127];
    for (int i = 0; i < 128; ++i)
        lv[i] = (i == 127) ? 4.0 : (-4.0 + (8.0 / 127.0) * (double)i);

    const double inv_sqrt2pi = 0.39894228040143267794;
    const double inv_sqrt2   = 0.70710678118654752440;
    const double pdf_end = exp(-0.5 * 30.0 * 30.0) * inv_sqrt2pi;
    const double cdf_m30 = 0.5 * (1.0 + erf(-30.0 * inv_sqrt2));
    const double cdf_p30 = 0.5 * (1.0 + erf( 30.0 * inv_sqrt2));

    for (int it = 0; it < 200; ++it) {
        for (int i = 0; i < 127; ++i) {
            double tt = 0.5 * (lv[i] + lv[i + 1]);
            tt = fmin(fmax(tt, -30.0), 30.0);
            bp[i] = exp(-0.5 * tt * tt) * inv_sqrt2pi;
            bc[i] = 0.5 * (1.0 + erf(tt * inv_sqrt2));
        }
        for (int i = 0; i < 128; ++i) {
            const double plo = (i == 0)   ? pdf_end : bp[i - 1];
            const double clo = (i == 0)   ? cdf_m30 : bc[i - 1];
            const double phi = (i == 127) ? pdf_end : bp[i];
            const double chi = (i == 127) ? cdf_p30 : bc[i];
            lv[i] = (plo - phi) / fmax(chi - clo, 1e-30);
        }
    }
    for (int i = 0; i < 128; ++i) out_args->cb[i] = (float)lv[i];
}

extern "C" void kernel_launch(void* const* d_in, const int* in_sizes, int n_in,
                              void* d_out, int out_size, void* d_ws, size_t ws_size,
                              hipStream_t stream) {
    const float* x   = (const float*)d_in[0];
    const float* rot = (const float*)d_in[1];
    const float* qjl = (const float*)d_in[2];
    float* out = (float*)d_out;
    (void)d_ws; (void)ws_size;

    const int nrows = in_sizes[0] >> 7;

    CbArg args;
    lloyd_host(&args);   // pure host math; deterministic per call

    turboquant_kernel<<<2048, 256, 0, stream>>>(x, rot, qjl, out, nrows, args);
}

// Round 16
// 195.095 us; speedup vs baseline: 1.0265x; 1.0265x over previous
//
#include <hip/hip_runtime.h>
#include <math.h>

// Pin FP contraction OFF (r8-r15 proven): every a*b+c stays rounded mul +
// rounded add. Explicit fmaf used only where exact (+-1).
#pragma clang fp contract(off)

#define EPSF 1e-10f
#define INV128 0.0078125f
#define C128 0.08838834764831845f   // np.float32(1/sqrt(128))

struct CbArg { float cb[128]; };

// ---------------- cross-lane primitives (r5/r9 HW-verified, pure DPP) -------
template<int CTRL>
__device__ __forceinline__ float fdpp(float v) {
    return __builtin_bit_cast(float,
        __builtin_amdgcn_update_dpp(0, __builtin_bit_cast(int, v), CTRL, 0xF, 0xF, true));
}
// xor4 as pure DPP: banks 0,2 take row_ror:4; banks 1,3 take row_ror:12.
__device__ __forceinline__ float dpp_xor4(float v) {
    const int x = __builtin_bit_cast(int, v);
    int t = __builtin_amdgcn_update_dpp(x, x, 0x124, 0xF, 0x5, false);
    t = __builtin_amdgcn_update_dpp(t, x, 0x12C, 0xF, 0xA, false);
    return __builtin_bit_cast(float, t);
}
// MODE 1: DPP (verified at runtime) | MODE 0: __shfl_xor fallback
template<int MODE, int D>
__device__ __forceinline__ float xl(float v) {
    if constexpr (MODE == 0)   return __shfl_xor(v, D, 64);
    else if constexpr (D == 1) return fdpp<0xB1>(v);   // quad_perm xor1
    else if constexpr (D == 2) return fdpp<0x4E>(v);   // quad_perm xor2
    else                       return dpp_xor4(v);     // xor4
}

__device__ __forceinline__ bool dpp_ok() {
    const int lane = threadIdx.x & 63;
    const float tv = __int_as_float(0x3f800000 + lane * 1024);
    bool ok = true;
    ok = ok && (__float_as_uint(xl<1,1>(tv)) == __float_as_uint(__shfl_xor(tv, 1, 64)));
    ok = ok && (__float_as_uint(xl<1,2>(tv)) == __float_as_uint(__shfl_xor(tv, 2, 64)));
    ok = ok && (__float_as_uint(xl<1,4>(tv)) == __float_as_uint(__shfl_xor(tv, 4, 64)));
    return __all((int)ok) != 0;
}

// ---------------------------------------------------------------------------
// Main kernel, E=16 layout, TWO groups interleaved per wave (r15 DAG) with
// register-fused reduction trees (bitwise-identical: same ops, same order).
// ---------------------------------------------------------------------------
__device__ __forceinline__ float lm_recon(const float4* __restrict__ tbl4, float v) {
    float cf = fminf(fmaxf(fmaf(v, 128.0f, 512.0f), 0.0f), 1023.0f);
    const float4 e = tbl4[(int)cf];
    return (e.x < v) ? e.z : e.y;   // searchsorted side='left'
}

__device__ __forceinline__ void fwht_in16(float* u) {
#pragma unroll
    for (int d = 1; d <= 8; d <<= 1)
#pragma unroll
        for (int j = 0; j < 16; ++j)
            if ((j & d) == 0) {
                const float a = u[j], b = u[j + d];
                u[j] = a + b; u[j + d] = a - b;
            }
}

// dual-group FWHT: phases interleaved for ILP; per-group order == r12/r15
template<int MODE>
__device__ __forceinline__ void fwht128g2(float* ua, float* ub,
                                          float s1, float s2, float s4) {
    fwht_in16(ua);
    fwht_in16(ub);
#pragma unroll
    for (int j = 0; j < 16; ++j) { const float p = xl<MODE,1>(ua[j]); ua[j] = fmaf(s1, ua[j], p); }
#pragma unroll
    for (int j = 0; j < 16; ++j) { const float p = xl<MODE,1>(ub[j]); ub[j] = fmaf(s1, ub[j], p); }
#pragma unroll
    for (int j = 0; j < 16; ++j) { const float p = xl<MODE,2>(ua[j]); ua[j] = fmaf(s2, ua[j], p); }
#pragma unroll
    for (int j = 0; j < 16; ++j) { const float p = xl<MODE,2>(ub[j]); ub[j] = fmaf(s2, ub[j], p); }
#pragma unroll
    for (int j = 0; j < 16; ++j) { const float p = xl<MODE,4>(ua[j]); ua[j] = fmaf(s4, ua[j], p); }
#pragma unroll
    for (int j = 0; j < 16; ++j) { const float p = xl<MODE,4>(ub[j]); ub[j] = fmaf(s4, ub[j], p); }
}

// fused sum-of-squares tree: t8[k] = (u[2k]*u[2k]) + (u[2k+1]*u[2k+1]) —
// identical multiplies + identical add order to r12's materialized q[] tree.
template<int MODE>
__device__ __forceinline__ float rtree_sq(const float* u) {
    float t8[8];
#pragma unroll
    for (int k = 0; k < 8; ++k) t8[k] = (u[2*k] * u[2*k]) + (u[2*k+1] * u[2*k+1]);
    float t4[4];
#pragma unroll
    for (int k = 0; k < 4; ++k) t4[k] = t8[2*k] + t8[2*k+1];
    const float t2a = t4[0] + t4[1];
    const float t2b = t4[2] + t4[3];
    float s = t2a + t2b;
    s += xl<MODE, 1>(s);
    s += xl<MODE, 2>(s);
    s += xl<MODE, 4>(s);
    return s;
}
// fused sum-of-products tree (same structure)
template<int MODE>
__device__ __forceinline__ float rtree_prod(const float* a, const float* b) {
    float t8[8];
#pragma unroll
    for (int k = 0; k < 8; ++k) t8[k] = (a[2*k] * b[2*k]) + (a[2*k+1] * b[2*k+1]);
    float t4[4];
#pragma unroll
    for (int k = 0; k < 4; ++k) t4[k] = t8[2*k] + t8[2*k+1];
    const float t2a = t4[0] + t4[1];
    const float t2b = t4[2] + t4[3];
    float s = t2a + t2b;
    s += xl<MODE, 1>(s);
    s += xl<MODE, 2>(s);
    s += xl<MODE, 4>(s);
    return s;
}

template<int MODE>
__device__ __forceinline__ void run_pairs(
        const float* __restrict__ x, float* __restrict__ out,
        const float* __restrict__ rot, const float* __restrict__ qjl,
        const float4* __restrict__ tbl4, int nrows) {
    const int t    = threadIdx.x;
    const int lane = t & 63;
    const int wid  = t >> 6;
    const int sub  = lane & 7;   // 8 lanes per row
    const int grp  = lane >> 3;  // 8 rows per wave-group

    const float s1 = (sub & 1) ? -1.0f : 1.0f;
    const float s2 = (sub & 2) ? -1.0f : 1.0f;
    const float s4 = (sub & 4) ? -1.0f : 1.0f;

    const int npairs  = nrows >> 4;    // pair P = groups {2P, 2P+1} = 16 rows
    const int wstride = gridDim.x * 4;

    for (int P = blockIdx.x * 4 + wid; P < npairs; P += wstride) {
        const int rowA = P * 16 + grp;
        const int rowB = P * 16 + 8 + grp;

        float ua[16], ub[16], qa[16], qb[16], c0[16];
        {
            const float* xa = x + (size_t)rowA * 128 + sub * 16;
            const float* xb = x + (size_t)rowB * 128 + sub * 16;
#pragma unroll
            for (int k = 0; k < 4; ++k) {
                const float4 v4 = ((const float4*)xa)[k];
                ua[4*k] = v4.x; ua[4*k+1] = v4.y; ua[4*k+2] = v4.z; ua[4*k+3] = v4.w;
            }
#pragma unroll
            for (int k = 0; k < 4; ++k) {
                const float4 v4 = ((const float4*)xb)[k];
                ub[4*k] = v4.x; ub[4*k+1] = v4.y; ub[4*k+2] = v4.z; ub[4*k+3] = v4.w;
            }
        }

        // ---- norms, unit vectors (fused trees) ----
        const float nua = sqrtf(rtree_sq<MODE>(ua));
        const float nub = sqrtf(rtree_sq<MODE>(ub));
        const float iua = 1.0f / (nua + EPSF);
        const float iub = 1.0f / (nub + EPSF);

#pragma unroll
        for (int k = 0; k < 4; ++k) {   // rs0 (global/L1, shared by A,B)
            const float4 v4 = ((const float4*)(rot + sub * 16))[k];
            c0[4*k] = v4.x; c0[4*k+1] = v4.y; c0[4*k+2] = v4.z; c0[4*k+3] = v4.w;
        }
#pragma unroll
        for (int j = 0; j < 16; ++j) {
            ua[j] = ua[j] * iua; ua[j] = ua[j] * c0[j];
            ub[j] = ub[j] * iub; ub[j] = ub[j] * c0[j];
        }

        // ---- rotation_fwd (normalized; feeds quantizer) ----
        fwht128g2<MODE>(ua, ub, s1, s2, s4);
#pragma unroll
        for (int j = 0; j < 16; ++j) { ua[j] *= C128; ub[j] *= C128; }
#pragma unroll
        for (int k = 0; k < 4; ++k) {   // rs1
            const float4 v4 = ((const float4*)(rot + 128 + sub * 16))[k];
            c0[4*k] = v4.x; c0[4*k+1] = v4.y; c0[4*k+2] = v4.z; c0[4*k+3] = v4.w;
        }
#pragma unroll
        for (int j = 0; j < 16; ++j) { ua[j] *= c0[j]; ub[j] *= c0[j]; }
        fwht128g2<MODE>(ua, ub, s1, s2, s4);
#pragma unroll
        for (int j = 0; j < 16; ++j) { ua[j] *= C128; ub[j] *= C128; }

        // ---- pass 1: numerical rms + LM quantize ----
        const float rmsa = sqrtf(rtree_sq<MODE>(ua)) * C128;
        const float rmsb = sqrtf(rtree_sq<MODE>(ub)) * C128;
        const float sia  = 1.0f / (rmsa + EPSF);
        const float sib  = 1.0f / (rmsb + EPSF);
#pragma unroll
        for (int j = 0; j < 16; ++j) qa[j] = lm_recon(tbl4, ua[j] * sia);   // r_A
#pragma unroll
        for (int j = 0; j < 16; ++j) qb[j] = lm_recon(tbl4, ub[j] * sib);   // r_B

        // ---- refined gamma (fused trees) ----
        const float numa = rtree_prod<MODE>(ua, qa);
        const float numb = rtree_prod<MODE>(ub, qb);
        const float dena = rtree_sq<MODE>(qa);
        const float denb = rtree_sq<MODE>(qb);
        const float ga  = numa / (dena + EPSF);
        const float gb  = numb / (denb + EPSF);
        const float gia = 1.0f / (ga + EPSF);
        const float gib = 1.0f / (gb + EPSF);

        // ---- MSE-stage quantize; residuals in pa/pb (qa/qb become rc) ----
        float pa[16], pb[16];
#pragma unroll
        for (int j = 0; j < 16; ++j) {
            const float tq = lm_recon(tbl4, ua[j] * gia);
            qa[j] = tq * ga;            // rc_A
            pa[j] = ua[j] - qa[j];
        }
#pragma unroll
        for (int j = 0; j < 16; ++j) {
            const float tq = lm_recon(tbl4, ub[j] * gib);
            qb[j] = tq * gb;            // rc_B
            pb[j] = ub[j] - qb[j];
        }
        const float resna = sqrtf(rtree_sq<MODE>(pa));
        const float resnb = sqrtf(rtree_sq<MODE>(pb));

        // ==== post-quantization (ulp-safe folds) ====
#pragma unroll
        for (int k = 0; k < 4; ++k) {   // qjl
            const float4 v4 = ((const float4*)(qjl + sub * 16))[k];
            c0[4*k] = v4.x; c0[4*k+1] = v4.y; c0[4*k+2] = v4.z; c0[4*k+3] = v4.w;
        }
#pragma unroll
        for (int j = 0; j < 16; ++j) { pa[j] = pa[j] * c0[j]; pb[j] = pb[j] * c0[j]; }
        fwht128g2<MODE>(pa, pb, s1, s2, s4);
#pragma unroll
        for (int j = 0; j < 16; ++j) {
            pa[j] = (pa[j] >= 0.0f) ? 1.0f : -1.0f;
            pb[j] = (pb[j] >= 0.0f) ? 1.0f : -1.0f;
        }
        fwht128g2<MODE>(pa, pb, s1, s2, s4);   // exact integers
        const float rsa = resna * INV128;
        const float rsb = resnb * INV128;
#pragma unroll
        for (int j = 0; j < 16; ++j) {
            const float ta2 = pa[j] * c0[j];
            const float tb2 = pb[j] * c0[j];
            pa[j] = fmaf(ta2, rsa, qa[j]);
            pb[j] = fmaf(tb2, rsb, qb[j]);
        }

        // ---- inverse rotation (folded scales) ----
        fwht128g2<MODE>(pa, pb, s1, s2, s4);
#pragma unroll
        for (int k = 0; k < 4; ++k) {   // rs1
            const float4 v4 = ((const float4*)(rot + 128 + sub * 16))[k];
            c0[4*k] = v4.x; c0[4*k+1] = v4.y; c0[4*k+2] = v4.z; c0[4*k+3] = v4.w;
        }
#pragma unroll
        for (int j = 0; j < 16; ++j) { pa[j] *= c0[j]; pb[j] *= c0[j]; }
        fwht128g2<MODE>(pa, pb, s1, s2, s4);
#pragma unroll
        for (int k = 0; k < 4; ++k) {   // rs0
            const float4 v4 = ((const float4*)(rot + sub * 16))[k];
            c0[4*k] = v4.x; c0[4*k+1] = v4.y; c0[4*k+2] = v4.z; c0[4*k+3] = v4.w;
        }
        const float fna = nua * INV128;
        const float fnb = nub * INV128;
#pragma unroll
        for (int j = 0; j < 16; ++j) {
            pa[j] = (pa[j] * c0[j]) * fna;
            pb[j] = (pb[j] * c0[j]) * fnb;
        }

        {
            float* oa = out + (size_t)rowA * 128 + sub * 16;
            float* ob = out + (size_t)rowB * 128 + sub * 16;
#pragma unroll
            for (int k = 0; k < 4; ++k) {
                float4 v4;
                v4.x = pa[4*k]; v4.y = pa[4*k+1]; v4.z = pa[4*k+2]; v4.w = pa[4*k+3];
                ((float4*)oa)[k] = v4;
            }
#pragma unroll
            for (int k = 0; k < 4; ++k) {
                float4 v4;
                v4.x = pb[4*k]; v4.y = pb[4*k+1]; v4.z = pb[4*k+2]; v4.w = pb[4*k+3];
                ((float4*)ob)[k] = v4;
            }
        }
    }
}

__global__ __launch_bounds__(256, 4) void turboquant_kernel(
        const float* __restrict__ x,
        const float* __restrict__ rot,
        const float* __restrict__ qjl,
        float* __restrict__ out,
        const int nrows,
        const CbArg args) {
    __shared__ float scb[128];
    __shared__ float sbnd[128];
    __shared__ float4 tbl4[1024];

    const int t = threadIdx.x;
    if (t < 128) scb[t] = args.cb[t];
    __syncthreads();
    if (t < 128) {
        const float INF = __int_as_float(0x7f800000);
        sbnd[t] = (t < 127) ? 0.5f * (scb[t] + scb[t + 1]) : INF;
    }
    __syncthreads();
    // direct cell table (r9/r11/r12-proven): at most one boundary per
    // 1/128-wide cell (min gap ~0.034); g = #bounds < cell_left.
    for (int c = t; c < 1024; c += 256) {
        const float cl = -4.0f + (float)c * 0.0078125f;
        int g = 0;
#pragma unroll
        for (int d = 64; d >= 1; d >>= 1) g += (sbnd[g + d - 1] < cl) ? d : 0;
        tbl4[c] = make_float4(sbnd[g], scb[g], scb[(g < 127) ? g + 1 : 127], 0.0f);
    }
    __syncthreads();

    if (dpp_ok())
        run_pairs<1>(x, out, rot, qjl, tbl4, nrows);
    else
        run_pairs<0>(x, out, rot, qjl, tbl4, nrows);
}

// ---------------------------------------------------------------------------
// Host-side Lloyd-Max (r12-proven): token-identical f64 formulas; runs during
// capture only; kernarg struct snapshotted into the graph node.
// ---------------------------------------------------------------------------
static void lloyd_host(CbArg* out_args) {
    double lv[128], bp[127], bc[127];
    for (int i = 0; i < 128; ++i)
        lv[i] = (i == 127) ? 4.0 : (-4.0 + (8.0 / 127.0) * (double)i);

    const double inv_sqrt2pi = 0.39894228040143267794;
    const double inv_sqrt2   = 0.70710678118654752440;
    const double pdf_end = exp(-0.5 * 30.0 * 30.0) * inv_sqrt2pi;
    const double cdf_m30 = 0.5 * (1.0 + erf(-30.0 * inv_sqrt2));
    const double cdf_p30 = 0.5 * (1.0 + erf( 30.0 * inv_sqrt2));

    for (int it = 0; it < 200; ++it) {
        for (int i = 0; i < 127; ++i) {
            double tt = 0.5 * (lv[i] + lv[i + 1]);
            tt = fmin(fmax(tt, -30.0), 30.0);
            bp[i] = exp(-0.5 * tt * tt) * inv_sqrt2pi;
            bc[i] = 0.5 * (1.0 + erf(tt * inv_sqrt2));
        }
        for (int i = 0; i < 128; ++i) {
            const double plo = (i == 0)   ? pdf_end : bp[i - 1];
            const double clo = (i == 0)   ? cdf_m30 : bc[i - 1];
            const double phi = (i == 127) ? pdf_end : bp[i];
            const double chi = (i == 127) ? cdf_p30 : bc[i];
            lv[i] = (plo - phi) / fmax(chi - clo, 1e-30);
        }
    }
    for (int i = 0; i < 128; ++i) out_args->cb[i] = (float)lv[i];
}

extern "C" void kernel_launch(void* const* d_in, const int* in_sizes, int n_in,
                              void* d_out, int out_size, void* d_ws, size_t ws_size,
                              hipStream_t stream) {
    const float* x   = (const float*)d_in[0];
    const float* rot = (const float*)d_in[1];
    const float* qjl = (const float*)d_in[2];
    float* out = (float*)d_out;
    (void)d_ws; (void)ws_size;

    const int nrows = in_sizes[0] >> 7;

    CbArg args;
    lloyd_host(&args);   // pure host math; deterministic per call

    turboquant_kernel<<<2048, 256, 0, stream>>>(x, rot, qjl, out, nrows, args);
}